// Round 8
// baseline (250.733 us; speedup 1.0000x reference)
//
#include <hip/hip_runtime.h>
#include <math.h>

#define NQ 14
#define NL 4
#define NS (1 << NQ)      // 16384 amplitudes (full state)
#define NT 1024           // threads per block
#define APT (NS / NT)

#define NTS 1024          // threads per split block
#define NSH 8192          // amplitudes per half-state (64 KB)

struct c32 { float x, y; };
__device__ __forceinline__ c32 cmul(c32 a, c32 b) { return {a.x*b.x - a.y*b.y, a.x*b.y + a.y*b.x}; }
__device__ __forceinline__ c32 cadd(c32 a, c32 b) { return {a.x + b.x, a.y + b.y}; }

__device__ __forceinline__ void gate8(c32* v, const float* U, const int s) {
    c32 u00={U[0],U[1]}, u01={U[2],U[3]}, u10={U[4],U[5]}, u11={U[6],U[7]};
    #pragma unroll
    for (int k = 0; k < 8; ++k) {
        if (k & s) continue;
        c32 A = v[k], B = v[k | s];
        v[k]     = cadd(cmul(u00, A), cmul(u01, B));
        v[k | s] = cadd(cmul(u10, A), cmul(u11, B));
    }
}

// Slot k holds logical element k^swbits: gate on slot-bit p uses role-swapped
// U'[i][j] = U[i^sw][j^sw], sw = bit p of the XOR label (r6-verified).
__device__ __forceinline__ void gate8sw(c32* v, const float* U, const int s, const int sw) {
    c32 u00 = sw ? c32{U[6],U[7]} : c32{U[0],U[1]};
    c32 u01 = sw ? c32{U[4],U[5]} : c32{U[2],U[3]};
    c32 u10 = sw ? c32{U[2],U[3]} : c32{U[4],U[5]};
    c32 u11 = sw ? c32{U[0],U[1]} : c32{U[6],U[7]};
    #pragma unroll
    for (int k = 0; k < 8; ++k) {
        if (k & s) continue;
        c32 A = v[k], B = v[k | s];
        v[k]     = cadd(cmul(u00, A), cmul(u01, B));
        v[k | s] = cadd(cmul(u10, A), cmul(u11, B));
    }
}

// ---------------------------------------------------------------------------
// Shared precompute: fused per-(layer,qubit) U = Rz*Ry*Rx, entangle phase
// tables (bits 0-12 only — qubit 0 is never an RZ target), encoding angles.
// ---------------------------------------------------------------------------
__device__ __forceinline__ void precompute(const float* x, const float* prx, const float* pry,
                                           const float* prz, const float* pent,
                                           float (*Um)[NQ][8], float (*tlo)[128], float (*thi)[64],
                                           float* encc, float* encs, int tid, int samp) {
    if (tid < NL*NQ) {
        int l = tid / NQ, q = tid % NQ;
        float hx = 0.5f*prx[l*NQ+q], hy = 0.5f*pry[l*NQ+q], hz = 0.5f*prz[l*NQ+q];
        float cx = cosf(hx), sx = sinf(hx);
        float cy = cosf(hy), sy = sinf(hy);
        float cz = cosf(hz), sz = sinf(hz);
        c32 m00 = { cy*cx,  sy*sx };
        c32 m01 = {-sy*cx, -cy*sx };
        c32 m10 = { sy*cx, -cy*sx };
        c32 m11 = { cy*cx, -sy*sx };
        c32 e0 = {cz, -sz}, e1 = {cz, sz};
        c32 u00 = cmul(e0, m00), u01 = cmul(e0, m01);
        c32 u10 = cmul(e1, m10), u11 = cmul(e1, m11);
        float* U = Um[l][q];
        U[0]=u00.x; U[1]=u00.y; U[2]=u01.x; U[3]=u01.y;
        U[4]=u10.x; U[5]=u10.y; U[6]=u11.x; U[7]=u11.y;
    } else if (tid >= 64 && tid < 64 + NL*192) {
        int t2 = tid - 64;
        int l = t2 / 192, r = t2 % 192;
        if (r < 128) {
            float a = 0.f;
            for (int p = 0; p < 7; ++p) {
                float th = 0.5f * pent[l*(NQ-1) + (12 - p)];
                a += ((r >> p) & 1) ? th : -th;
            }
            tlo[l][r] = a;
        } else {
            int m = r - 128;
            float a = 0.f;
            for (int p = 0; p < 6; ++p) {
                float th = 0.5f * pent[l*(NQ-1) + (5 - p)];
                a += ((m >> p) & 1) ? th : -th;
            }
            thi[l][m] = a;
        }
    } else if (tid >= 960 && tid < 960 + NQ) {
        int i = tid - 960;
        float th = tanhf(x[samp*NQ + i]) * 3.14159265358979323846f;
        encc[i] = cosf(0.5f*th);
        encs[i] = sinf(0.5f*th);
    }
}

// ===========================================================================
// SPLIT KERNEL: 2 blocks per sample, half-state (bit13 = blockIdx&1) in LDS.
// Entangle perm preserves bit13; local source a = (z ^ (z>>1)) ^ (h<<12).
// Qubit-0 rotation = elementwise cross-half mix, fused into sweep A reads;
// the partner dump is fused into the previous gather's writes (dual store).
// ===========================================================================

__device__ __forceinline__ void flag_set(int* p, int v) {
    __threadfence();
    __hip_atomic_store(p, v, __ATOMIC_RELEASE, __HIP_MEMORY_SCOPE_AGENT);
}
__device__ __forceinline__ void flag_wait(int* p, int v) {
    while (__hip_atomic_load(p, __ATOMIC_ACQUIRE, __HIP_MEMORY_SCOPE_AGENT) != v)
        __builtin_amdgcn_s_sleep(2);
    __threadfence();
}

template<int PB>
__device__ __forceinline__ void sweepS3(float2* st, const float* U2, const float* U1,
                                        const float* U0s, int tid) {
    const int ib = ((tid >> PB) << (PB+3)) | (tid & ((1 << PB) - 1));
    c32 v[8];
    #pragma unroll
    for (int k = 0; k < 8; ++k) { float2 f = st[ib + (k << PB)]; v[k] = {f.x, f.y}; }
    gate8(v, U2, 4); gate8(v, U1, 2); gate8(v, U0s, 1);
    #pragma unroll
    for (int k = 0; k < 8; ++k) st[ib + (k << PB)] = make_float2(v[k].x, v[k].y);
}

__device__ __forceinline__ void sweepS1(float2* st, const float* U, int tid) {
    c32 u00={U[0],U[1]}, u01={U[2],U[3]}, u10={U[4],U[5]}, u11={U[6],U[7]};
    #pragma unroll
    for (int m = 0; m < 4; ++m) {
        int u = tid + m*NTS;
        int i = ((u >> 3) << 4) | (u & 7);
        float2 f0 = st[i], f1 = st[i | 8];
        c32 A = {f0.x, f0.y}, B = {f1.x, f1.y};
        c32 r0 = cadd(cmul(u00, A), cmul(u01, B));
        c32 r1 = cadd(cmul(u10, A), cmul(u11, B));
        st[i]     = make_float2(r0.x, r0.y);
        st[i | 8] = make_float2(r1.x, r1.y);
    }
}

// Sweep A (layers 1-3): qubit-0 cross-half mix + gates on bits 2,1,0
// (qubits 11,12,13) over the thread's own 8 contiguous amps (XOR order).
__device__ __forceinline__ void sweepSA(float2* st, const float2* pd, const float* Uq0,
                                        const float* U11, const float* U12, const float* U13,
                                        int tid, int h) {
    const int t7 = tid & 7;
    const int base = tid << 3;
    c32 cm = h ? c32{Uq0[6], Uq0[7]} : c32{Uq0[0], Uq0[1]};  // U[h][h]
    c32 cp = h ? c32{Uq0[4], Uq0[5]} : c32{Uq0[2], Uq0[3]};  // U[h][1-h]
    c32 p[8];
    #pragma unroll
    for (int s = 0; s < 8; ++s) { float2 g = pd[base | (s ^ t7)]; p[s] = {g.x, g.y}; }
    c32 v[8];
    #pragma unroll
    for (int s = 0; s < 8; ++s) {
        float2 f = st[base | (s ^ t7)];
        v[s] = cadd(cmul(cm, c32{f.x, f.y}), cmul(cp, p[s]));
    }
    gate8sw(v, U11, 4, (t7 >> 2) & 1);
    gate8sw(v, U12, 2, (t7 >> 1) & 1);
    gate8sw(v, U13, 1,  t7       & 1);
    #pragma unroll
    for (int s = 0; s < 8; ++s) st[base | (s ^ t7)] = make_float2(v[s].x, v[s].y);
}

// Materialized entangle gather + dual store (LDS + my global dump region).
__device__ __forceinline__ void gatherS(float2* st, float2* myd, const float* phlo,
                                        const float* phhi, int tid, int hb12) {
    c32 tmp[8];
    #pragma unroll
    for (int m = 0; m < 8; ++m) {
        int z = tid + m*NTS;
        int a = (z ^ (z >> 1)) ^ hb12;
        float2 f = st[a];
        float ang = phlo[z & 127] + phhi[(z >> 7) & 63];
        float sn, cs;
        __sincosf(ang, &sn, &cs);
        tmp[m] = { cs*f.x - sn*f.y, cs*f.y + sn*f.x };
    }
    __syncthreads();
    #pragma unroll
    for (int m = 0; m < 8; ++m) {
        int z = tid + m*NTS;
        float2 val = make_float2(tmp[m].x, tmp[m].y);
        st[z]  = val;   // coalesced LDS write
        myd[z] = val;   // coalesced global dump (partner reads next layer)
    }
}

__global__ __launch_bounds__(NTS)
void qc_split(const float* __restrict__ x,
              const float* __restrict__ prx,
              const float* __restrict__ pry,
              const float* __restrict__ prz,
              const float* __restrict__ pent,
              float* __restrict__ out,
              float2* __restrict__ pdata,
              int* __restrict__ dumpF,
              int* __restrict__ consF,
              float* __restrict__ part)
{
    __shared__ float2 st[NSH];           // 64 KB half-state
    __shared__ float  Um[NL][NQ][8];
    __shared__ float  tlo[NL][128];
    __shared__ float  thi[NL][64];
    __shared__ float  encc[NQ], encs[NQ];
    __shared__ float  red[NTS/64][NQ];

    const int tid  = threadIdx.x;
    const int bid  = blockIdx.x;
    const int samp = bid >> 1;
    const int h    = bid & 1;
    const int pb   = bid ^ 1;
    const int hb12 = h << 12;
    float2* myd      = pdata + (size_t)bid * NSH;
    const float2* pd = pdata + (size_t)pb  * NSH;

    precompute(x, prx, pry, prz, pent, Um, tlo, thi, encc, encs, tid, samp);
    __syncthreads();

    // ---- init: product state w/ layer-0 qubit-0 rotation folded in, plus
    //      layer-0 gates on qubits 11,12,13 (bits 2,1,0), all in-register ----
    {
        const int t7 = tid & 7;
        const int base = tid << 3;
        const float* U0 = Um[0][0];
        float c0 = encc[0], s0 = encs[0];
        c32 vh = h ? c32{U0[4]*c0 + U0[6]*s0, U0[5]*c0 + U0[7]*s0}
                   : c32{U0[0]*c0 + U0[2]*s0, U0[1]*c0 + U0[3]*s0};
        float ph = 1.f;
        #pragma unroll
        for (int p = 3; p <= 12; ++p)        // z bits 3..12 from tid; qubit 13-p
            ph *= ((tid >> (p-3)) & 1) ? encs[13-p] : encc[13-p];
        c32 v[8];
        #pragma unroll
        for (int s = 0; s < 8; ++s) {
            int e = s ^ t7;
            float f = ph * ((e & 4) ? encs[11] : encc[11])
                         * ((e & 2) ? encs[12] : encc[12])
                         * ((e & 1) ? encs[13] : encc[13]);
            v[s] = { vh.x * f, vh.y * f };
        }
        gate8sw(v, Um[0][11], 4, (t7 >> 2) & 1);
        gate8sw(v, Um[0][12], 2, (t7 >> 1) & 1);
        gate8sw(v, Um[0][13], 1,  t7       & 1);
        #pragma unroll
        for (int s = 0; s < 8; ++s) st[base | (s ^ t7)] = make_float2(v[s].x, v[s].y);
    }
    __syncthreads();

    // ---- layer 0: remaining rotations + entangle gather (dump #1) ----
    sweepS3<10>(st, Um[0][1], Um[0][2], Um[0][3], tid); __syncthreads();  // q1,2,3
    sweepS3<7 >(st, Um[0][4], Um[0][5], Um[0][6], tid); __syncthreads();  // q4,5,6
    sweepS3<4 >(st, Um[0][7], Um[0][8], Um[0][9], tid); __syncthreads();  // q7,8,9
    sweepS1(st, Um[0][10], tid); __syncthreads();                          // q10
    gatherS(st, myd, tlo[0], thi[0], tid, hb12);
    __syncthreads();
    if (tid == 0) flag_set(&dumpF[bid], 1);

    // ---- layers 1..3 ----
    #pragma unroll 1
    for (int l = 1; l < NL; ++l) {
        if (tid == 0) flag_wait(&dumpF[pb], l);
        __syncthreads();
        sweepSA(st, pd, Um[l][0], Um[l][11], Um[l][12], Um[l][13], tid, h);
        __syncthreads();
        if (l < 3 && tid == 0) flag_set(&consF[bid], l);   // partner may overwrite its dump
        sweepS3<10>(st, Um[l][1], Um[l][2], Um[l][3], tid); __syncthreads();
        sweepS3<7 >(st, Um[l][4], Um[l][5], Um[l][6], tid); __syncthreads();
        sweepS3<4 >(st, Um[l][7], Um[l][8], Um[l][9], tid); __syncthreads();
        sweepS1(st, Um[l][10], tid); __syncthreads();
        if (l < 3) {
            if (tid == 0) flag_wait(&consF[pb], l);        // partner consumed my dump #l
            __syncthreads();
            gatherS(st, myd, tlo[l], thi[l], tid, hb12);
            __syncthreads();
            if (tid == 0) flag_set(&dumpF[bid], l + 1);
        }
    }

    // ---- epilogue: layer-3 gather+phase fused with <Z_i>; cross-block combine ----
    float acc[NQ];
    #pragma unroll
    for (int i = 0; i < NQ; ++i) acc[i] = 0.f;
    #pragma unroll
    for (int m = 0; m < 8; ++m) {
        int z = tid + m*NTS;
        int a = (z ^ (z >> 1)) ^ hb12;
        float2 f = st[a];
        float ang = tlo[NL-1][z & 127] + thi[NL-1][(z >> 7) & 63];
        float sn, cs;
        __sincosf(ang, &sn, &cs);
        float re = cs*f.x - sn*f.y;
        float im = cs*f.y + sn*f.x;
        float pr = re*re + im*im;
        acc[0] += h ? -pr : pr;              // qubit 0 = bit 13 = h
        #pragma unroll
        for (int p = 0; p <= 12; ++p)        // qubit 13-p at local bit p
            acc[13-p] += ((z >> p) & 1) ? -pr : pr;
    }
    #pragma unroll
    for (int off = 32; off >= 1; off >>= 1) {
        #pragma unroll
        for (int i = 0; i < NQ; ++i)
            acc[i] += __shfl_down(acc[i], off, 64);
    }
    const int wid = tid >> 6, lane = tid & 63;
    if (lane == 0) {
        #pragma unroll
        for (int i = 0; i < NQ; ++i) red[wid][i] = acc[i];
    }
    __syncthreads();
    float s = 0.f;
    if (tid < NQ) {
        #pragma unroll
        for (int w = 0; w < NTS/64; ++w) s += red[w][tid];
    }
    if (h == 1) {
        if (tid < NQ) part[bid*16 + tid] = s;
        __syncthreads();
        if (tid == 0) flag_set(&dumpF[bid], 4);
    } else {
        if (tid == 0) flag_wait(&dumpF[pb], 4);
        __syncthreads();
        if (tid < NQ) out[samp*NQ + tid] = s + part[pb*16 + tid];
    }
}

// ===========================================================================
// FALLBACK (round-7 kernel, verified): one block per sample, full state.
// Used only if ws_size is too small for the split path.
// ===========================================================================
template<int L> __device__ __forceinline__ int permP(int y) {
    if constexpr (L == 0) return y;
    else if constexpr (L == 1) return y ^ (y >> 1);
    else if constexpr (L == 2) return y ^ (y >> 2);
    else if constexpr (L == 3) { int t = y ^ (y >> 1); return t ^ (t >> 2); }
    else return y ^ (y >> 4);
}

template<int L, int PB, bool FUSE>
__device__ __forceinline__ void sweep3(float2* st, const float* U2, const float* U1,
                                       const float* U0, const float* phlo, const float* phhi, int tid) {
    #pragma unroll 1
    for (int m = 0; m < 2; ++m) {
        const int t  = tid + m*NT;
        const int ib = ((t >> PB) << (PB+3)) | (t & ((1 << PB) - 1));
        c32 v[8]; int ad[8];
        #pragma unroll
        for (int k = 0; k < 8; ++k) {
            int y = ib + (k << PB);
            int a = permP<L>(y);
            ad[k] = a;
            float2 f = st[a];
            c32 vv = {f.x, f.y};
            if constexpr (FUSE) {
                float ang = phlo[y & 127] + phhi[(y >> 7) & 63];
                float sn, cs;
                __sincosf(ang, &sn, &cs);
                vv = { cs*vv.x - sn*vv.y, cs*vv.y + sn*vv.x };
            }
            v[k] = vv;
        }
        gate8(v, U2, 4); gate8(v, U1, 2); gate8(v, U0, 1);
        #pragma unroll
        for (int k = 0; k < 8; ++k) st[ad[k]] = make_float2(v[k].x, v[k].y);
    }
}

template<int L>
__device__ __forceinline__ void sweep2_43(float2* st, const float* U4, const float* U3, int tid) {
    #pragma unroll 1
    for (int m = 0; m < 4; ++m) {
        const int t  = tid + m*NT;
        const int ib = ((t >> 3) << 5) | (t & 7);
        c32 v[4]; int ad[4];
        #pragma unroll
        for (int k = 0; k < 4; ++k) {
            int y = ib + ((k & 1) << 3) + ((k >> 1) << 4);
            int a = permP<L>(y);
            ad[k] = a;
            float2 f = st[a];
            v[k] = {f.x, f.y};
        }
        {
            c32 u00={U4[0],U4[1]}, u01={U4[2],U4[3]}, u10={U4[4],U4[5]}, u11={U4[6],U4[7]};
            #pragma unroll
            for (int k = 0; k < 4; ++k) {
                if (k & 2) continue;
                c32 A = v[k], B = v[k|2];
                v[k]   = cadd(cmul(u00,A), cmul(u01,B));
                v[k|2] = cadd(cmul(u10,A), cmul(u11,B));
            }
        }
        {
            c32 u00={U3[0],U3[1]}, u01={U3[2],U3[3]}, u10={U3[4],U3[5]}, u11={U3[6],U3[7]};
            #pragma unroll
            for (int k = 0; k < 4; ++k) {
                if (k & 1) continue;
                c32 A = v[k], B = v[k|1];
                v[k]   = cadd(cmul(u00,A), cmul(u01,B));
                v[k|1] = cadd(cmul(u10,A), cmul(u11,B));
            }
        }
        #pragma unroll
        for (int k = 0; k < 4; ++k) st[ad[k]] = make_float2(v[k].x, v[k].y);
    }
}

template<int L>
__device__ __forceinline__ void sweep_own(float2* st, const float* U11, const float* U12,
                                          const float* U13, int tid) {
    const int t4   = tid & 15;
    const int base = tid << 4;
    #pragma unroll 1
    for (int m = 0; m < 2; ++m) {
        c32 v[8]; int ad[8];
        #pragma unroll
        for (int s = 0; s < 8; ++s) {
            int e = ((m << 3) | s) ^ t4;
            int a = permP<L>(base | e);
            ad[s] = a;
            float2 f = st[a];
            v[s] = {f.x, f.y};
        }
        gate8sw(v, U11, 4, (t4 >> 2) & 1);
        gate8sw(v, U12, 2, (t4 >> 1) & 1);
        gate8sw(v, U13, 1,  t4       & 1);
        #pragma unroll
        for (int s = 0; s < 8; ++s) st[ad[s]] = make_float2(v[s].x, v[s].y);
    }
}

template<int L>
__device__ __forceinline__ void do_layer(float2* st, float (*UmL)[8],
                                         const float* phlo, const float* phhi, int tid) {
    constexpr bool F = (L > 0);
    sweep3<L, 11, F>(st, UmL[0], UmL[1], UmL[2], phlo, phhi, tid);
    __syncthreads();
    sweep3<L, 8, false>(st, UmL[3], UmL[4], UmL[5], nullptr, nullptr, tid);
    __syncthreads();
    sweep3<L, 5, false>(st, UmL[6], UmL[7], UmL[8], nullptr, nullptr, tid);
    __syncthreads();
    sweep2_43<L>(st, UmL[9], UmL[10], tid);
    __syncthreads();
    sweep_own<L>(st, UmL[11], UmL[12], UmL[13], tid);
    __syncthreads();
}

__global__ __launch_bounds__(NT) __attribute__((amdgpu_waves_per_eu(4, 4)))
void qc_kernel(const float* __restrict__ x,
               const float* __restrict__ prx,
               const float* __restrict__ pry,
               const float* __restrict__ prz,
               const float* __restrict__ pent,
               float* __restrict__ out)
{
    __shared__ float2 st[NS];
    __shared__ float  Um[NL][NQ][8];
    __shared__ float  tlo[NL][128];
    __shared__ float  thi[NL][64];
    __shared__ float  encc[NQ], encs[NQ];
    __shared__ float  red[NT/64][NQ];

    const int tid = threadIdx.x;
    const int b   = blockIdx.x;

    precompute(x, prx, pry, prz, pent, Um, tlo, thi, encc, encs, tid, b);
    __syncthreads();

    {
        float prodLow = 1.f;
        #pragma unroll
        for (int p = 0; p < 10; ++p)
            prodLow *= ((tid >> p) & 1) ? encs[13-p] : encc[13-p];
        #pragma unroll
        for (int j = 0; j < APT; ++j) {
            float a = prodLow;
            a *= (j & 1) ? encs[3] : encc[3];
            a *= (j & 2) ? encs[2] : encc[2];
            a *= (j & 4) ? encs[1] : encc[1];
            a *= (j & 8) ? encs[0] : encc[0];
            st[tid + j*NT] = make_float2(a, 0.f);
        }
    }
    __syncthreads();

    do_layer<0>(st, Um[0], nullptr, nullptr, tid);
    do_layer<1>(st, Um[1], tlo[0], thi[0], tid);
    do_layer<2>(st, Um[2], tlo[1], thi[1], tid);
    do_layer<3>(st, Um[3], tlo[2], thi[2], tid);

    float acc[NQ];
    #pragma unroll
    for (int i = 0; i < NQ; ++i) acc[i] = 0.f;
    #pragma unroll
    for (int j = 0; j < APT; ++j) {
        int y = tid + j*NT;
        int a = permP<4>(y);
        float2 v = st[a];
        float ang = tlo[NL-1][y & 127] + thi[NL-1][(y >> 7) & 63];
        float sn, cs;
        __sincosf(ang, &sn, &cs);
        float re = cs*v.x - sn*v.y;
        float im = cs*v.y + sn*v.x;
        float pr = re*re + im*im;
        #pragma unroll
        for (int p = 0; p < NQ; ++p)
            acc[NQ-1-p] += ((y >> p) & 1) ? -pr : pr;
    }
    #pragma unroll
    for (int off = 32; off >= 1; off >>= 1) {
        #pragma unroll
        for (int i = 0; i < NQ; ++i)
            acc[i] += __shfl_down(acc[i], off, 64);
    }
    const int wid = tid >> 6, lane = tid & 63;
    if (lane == 0) {
        #pragma unroll
        for (int i = 0; i < NQ; ++i) red[wid][i] = acc[i];
    }
    __syncthreads();
    if (tid < NQ) {
        float s = 0.f;
        #pragma unroll
        for (int w = 0; w < NT/64; ++w) s += red[w][tid];
        out[b*NQ + tid] = s;
    }
}

extern "C" void kernel_launch(void* const* d_in, const int* in_sizes, int n_in,
                              void* d_out, int out_size, void* d_ws, size_t ws_size,
                              hipStream_t stream) {
    (void)n_in; (void)out_size;
    const float* x    = (const float*)d_in[0];
    const float* prx  = (const float*)d_in[1];
    const float* pry  = (const float*)d_in[2];
    const float* prz  = (const float*)d_in[3];
    const float* pent = (const float*)d_in[4];
    float* out = (float*)d_out;
    const int B = in_sizes[0] / NQ;
    const int nb = 2 * B;

    const size_t pdataBytes = (size_t)nb * NSH * sizeof(float2);     // 16 MB @ B=128
    const size_t flagsOff   = pdataBytes;                            // dumpF[nb]
    const size_t consOff    = flagsOff + 2048;                       // consF[nb]
    const size_t partOff    = flagsOff + 4096;                       // part[nb*16]
    const size_t need       = partOff + (size_t)nb * 16 * sizeof(float);

    if (ws_size >= need) {
        char* wsb = (char*)d_ws;
        float2* pdata = (float2*)wsb;
        int*    dumpF = (int*)(wsb + flagsOff);
        int*    consF = (int*)(wsb + consOff);
        float*  part  = (float*)(wsb + partOff);
        hipMemsetAsync(wsb + flagsOff, 0, 4096, stream);             // zero flags each launch
        qc_split<<<nb, NTS, 0, stream>>>(x, prx, pry, prz, pent, out,
                                         pdata, dumpF, consF, part);
    } else {
        qc_kernel<<<B, NT, 0, stream>>>(x, prx, pry, prz, pent, out);
    }
}

// Round 9
// 247.257 us; speedup vs baseline: 1.0141x; 1.0141x over previous
//
#include <hip/hip_runtime.h>
#include <math.h>

#define NQ 14
#define NL 4
#define NS (1 << NQ)      // 16384 amplitudes (full state)
#define NT 1024           // threads per block
#define APT (NS / NT)

#define NTS 1024          // threads per split block
#define NSH 8192          // amplitudes per half-state (64 KB)

struct c32 { float x, y; };
__device__ __forceinline__ c32 cmul(c32 a, c32 b) { return {a.x*b.x - a.y*b.y, a.x*b.y + a.y*b.x}; }
__device__ __forceinline__ c32 cadd(c32 a, c32 b) { return {a.x + b.x, a.y + b.y}; }

__device__ __forceinline__ void gate8(c32* v, const float* U, const int s) {
    c32 u00={U[0],U[1]}, u01={U[2],U[3]}, u10={U[4],U[5]}, u11={U[6],U[7]};
    #pragma unroll
    for (int k = 0; k < 8; ++k) {
        if (k & s) continue;
        c32 A = v[k], B = v[k | s];
        v[k]     = cadd(cmul(u00, A), cmul(u01, B));
        v[k | s] = cadd(cmul(u10, A), cmul(u11, B));
    }
}

// Slot k holds logical element k^swbits: gate on slot-bit p uses role-swapped
// U'[i][j] = U[i^sw][j^sw], sw = bit p of the XOR label (r6-verified).
__device__ __forceinline__ void gate8sw(c32* v, const float* U, const int s, const int sw) {
    c32 u00 = sw ? c32{U[6],U[7]} : c32{U[0],U[1]};
    c32 u01 = sw ? c32{U[4],U[5]} : c32{U[2],U[3]};
    c32 u10 = sw ? c32{U[2],U[3]} : c32{U[4],U[5]};
    c32 u11 = sw ? c32{U[0],U[1]} : c32{U[6],U[7]};
    #pragma unroll
    for (int k = 0; k < 8; ++k) {
        if (k & s) continue;
        c32 A = v[k], B = v[k | s];
        v[k]     = cadd(cmul(u00, A), cmul(u01, B));
        v[k | s] = cadd(cmul(u10, A), cmul(u11, B));
    }
}

// ---------------------------------------------------------------------------
// Shared precompute: fused per-(layer,qubit) U = Rz*Ry*Rx, entangle phase
// tables (bits 0-12 only — qubit 0 is never an RZ target), encoding angles.
// ---------------------------------------------------------------------------
__device__ __forceinline__ void precompute(const float* x, const float* prx, const float* pry,
                                           const float* prz, const float* pent,
                                           float (*Um)[NQ][8], float (*tlo)[128], float (*thi)[64],
                                           float* encc, float* encs, int tid, int samp) {
    if (tid < NL*NQ) {
        int l = tid / NQ, q = tid % NQ;
        float hx = 0.5f*prx[l*NQ+q], hy = 0.5f*pry[l*NQ+q], hz = 0.5f*prz[l*NQ+q];
        float cx = cosf(hx), sx = sinf(hx);
        float cy = cosf(hy), sy = sinf(hy);
        float cz = cosf(hz), sz = sinf(hz);
        c32 m00 = { cy*cx,  sy*sx };
        c32 m01 = {-sy*cx, -cy*sx };
        c32 m10 = { sy*cx, -cy*sx };
        c32 m11 = { cy*cx, -sy*sx };
        c32 e0 = {cz, -sz}, e1 = {cz, sz};
        c32 u00 = cmul(e0, m00), u01 = cmul(e0, m01);
        c32 u10 = cmul(e1, m10), u11 = cmul(e1, m11);
        float* U = Um[l][q];
        U[0]=u00.x; U[1]=u00.y; U[2]=u01.x; U[3]=u01.y;
        U[4]=u10.x; U[5]=u10.y; U[6]=u11.x; U[7]=u11.y;
    } else if (tid >= 64 && tid < 64 + NL*192) {
        int t2 = tid - 64;
        int l = t2 / 192, r = t2 % 192;
        if (r < 128) {
            float a = 0.f;
            for (int p = 0; p < 7; ++p) {
                float th = 0.5f * pent[l*(NQ-1) + (12 - p)];
                a += ((r >> p) & 1) ? th : -th;
            }
            tlo[l][r] = a;
        } else {
            int m = r - 128;
            float a = 0.f;
            for (int p = 0; p < 6; ++p) {
                float th = 0.5f * pent[l*(NQ-1) + (5 - p)];
                a += ((m >> p) & 1) ? th : -th;
            }
            thi[l][m] = a;
        }
    } else if (tid >= 960 && tid < 960 + NQ) {
        int i = tid - 960;
        float th = tanhf(x[samp*NQ + i]) * 3.14159265358979323846f;
        encc[i] = cosf(0.5f*th);
        encs[i] = sinf(0.5f*th);
    }
}

// ===========================================================================
// SPLIT KERNEL: 2 blocks per sample, half-state (bit13 = h) in LDS.
// bid = h*128 + samp so partner (bid^128) maps to the SAME XCD under the
// bid%8 round-robin — the 64 KB exchange stays in that XCD's 4 MB L2.
// Qubit-0 rotation = elementwise cross-half mix fused into sweepSA reads;
// partner dump fused into the previous gather's writes (dual store).
// ===========================================================================

__device__ __forceinline__ void flag_set(int* p, int v) {
    __threadfence();
    __hip_atomic_store(p, v, __ATOMIC_RELEASE, __HIP_MEMORY_SCOPE_AGENT);
}
__device__ __forceinline__ void flag_wait(int* p, int v) {
    while (__hip_atomic_load(p, __ATOMIC_ACQUIRE, __HIP_MEMORY_SCOPE_AGENT) != v)
        __builtin_amdgcn_s_sleep(2);
    __threadfence();
}

template<int PB>
__device__ __forceinline__ void sweepS3(float2* st, const float* U2, const float* U1,
                                        const float* U0s, int tid) {
    const int ib = ((tid >> PB) << (PB+3)) | (tid & ((1 << PB) - 1));
    c32 v[8];
    #pragma unroll
    for (int k = 0; k < 8; ++k) { float2 f = st[ib + (k << PB)]; v[k] = {f.x, f.y}; }
    gate8(v, U2, 4); gate8(v, U1, 2); gate8(v, U0s, 1);
    #pragma unroll
    for (int k = 0; k < 8; ++k) st[ib + (k << PB)] = make_float2(v[k].x, v[k].y);
}

__device__ __forceinline__ void sweepS1(float2* st, const float* U, int tid) {
    c32 u00={U[0],U[1]}, u01={U[2],U[3]}, u10={U[4],U[5]}, u11={U[6],U[7]};
    #pragma unroll
    for (int m = 0; m < 4; ++m) {
        int u = tid + m*NTS;
        int i = ((u >> 3) << 4) | (u & 7);
        float2 f0 = st[i], f1 = st[i | 8];
        c32 A = {f0.x, f0.y}, B = {f1.x, f1.y};
        c32 r0 = cadd(cmul(u00, A), cmul(u01, B));
        c32 r1 = cadd(cmul(u10, A), cmul(u11, B));
        st[i]     = make_float2(r0.x, r0.y);
        st[i | 8] = make_float2(r1.x, r1.y);
    }
}

// Sweep A (layers 1-3): qubit-0 cross-half mix + gates on bits 2,1,0
// (qubits 11,12,13). SPILL-FREE form: partner loads land in v[8] (the only
// 8-wide live array), then LDS values are mixed in element-by-element.
__device__ __forceinline__ void sweepSA(float2* st, const float2* pd, const float* Uq0,
                                        const float* U11, const float* U12, const float* U13,
                                        int tid, int h) {
    const int t7 = tid & 7;
    const int base = tid << 3;
    c32 cm = h ? c32{Uq0[6], Uq0[7]} : c32{Uq0[0], Uq0[1]};  // U[h][h]
    c32 cp = h ? c32{Uq0[4], Uq0[5]} : c32{Uq0[2], Uq0[3]};  // U[h][1-h]
    c32 v[8];
    #pragma unroll
    for (int s = 0; s < 8; ++s) { float2 g = pd[base | (s ^ t7)]; v[s] = {g.x, g.y}; }
    #pragma unroll
    for (int s = 0; s < 8; ++s) {
        float2 f = st[base | (s ^ t7)];
        v[s] = cadd(cmul(cm, c32{f.x, f.y}), cmul(cp, v[s]));
    }
    gate8sw(v, U11, 4, (t7 >> 2) & 1);
    gate8sw(v, U12, 2, (t7 >> 1) & 1);
    gate8sw(v, U13, 1,  t7       & 1);
    #pragma unroll
    for (int s = 0; s < 8; ++s) st[base | (s ^ t7)] = make_float2(v[s].x, v[s].y);
}

// Materialized entangle gather + dual store (LDS + my global dump region).
__device__ __forceinline__ void gatherS(float2* st, float2* myd, const float* phlo,
                                        const float* phhi, int tid, int hb12) {
    c32 tmp[8];
    #pragma unroll
    for (int m = 0; m < 8; ++m) {
        int z = tid + m*NTS;
        int a = (z ^ (z >> 1)) ^ hb12;
        float2 f = st[a];
        float ang = phlo[z & 127] + phhi[(z >> 7) & 63];
        float sn, cs;
        __sincosf(ang, &sn, &cs);
        tmp[m] = { cs*f.x - sn*f.y, cs*f.y + sn*f.x };
    }
    __syncthreads();
    #pragma unroll
    for (int m = 0; m < 8; ++m) {
        int z = tid + m*NTS;
        float2 val = make_float2(tmp[m].x, tmp[m].y);
        st[z]  = val;   // coalesced LDS write
        myd[z] = val;   // coalesced global dump (partner reads next layer)
    }
}

__global__ __launch_bounds__(NTS)
void qc_split(const float* __restrict__ x,
              const float* __restrict__ prx,
              const float* __restrict__ pry,
              const float* __restrict__ prz,
              const float* __restrict__ pent,
              float* __restrict__ out,
              float2* __restrict__ pdata,
              int* __restrict__ dumpF,
              int* __restrict__ consF,
              float* __restrict__ part)
{
    __shared__ float2 st[NSH];           // 64 KB half-state
    __shared__ float  Um[NL][NQ][8];
    __shared__ float  tlo[NL][128];
    __shared__ float  thi[NL][64];
    __shared__ float  encc[NQ], encs[NQ];
    __shared__ float  red[NTS/64][NQ];

    const int tid  = threadIdx.x;
    const int bid  = blockIdx.x;
    const int samp = bid & 127;          // bid = h*128 + samp
    const int h    = bid >> 7;
    const int pb   = bid ^ 128;          // same XCD under bid%8 round-robin
    const int hb12 = h << 12;
    float2* myd      = pdata + (size_t)bid * NSH;
    const float2* pd = pdata + (size_t)pb  * NSH;

    precompute(x, prx, pry, prz, pent, Um, tlo, thi, encc, encs, tid, samp);
    __syncthreads();

    // ---- init: product state w/ layer-0 qubit-0 rotation folded in, plus
    //      layer-0 gates on qubits 11,12,13 (bits 2,1,0), all in-register ----
    {
        const int t7 = tid & 7;
        const int base = tid << 3;
        const float* U0 = Um[0][0];
        float c0 = encc[0], s0 = encs[0];
        c32 vh = h ? c32{U0[4]*c0 + U0[6]*s0, U0[5]*c0 + U0[7]*s0}
                   : c32{U0[0]*c0 + U0[2]*s0, U0[1]*c0 + U0[3]*s0};
        float ph = 1.f;
        #pragma unroll
        for (int p = 3; p <= 12; ++p)        // z bits 3..12 from tid; qubit 13-p
            ph *= ((tid >> (p-3)) & 1) ? encs[13-p] : encc[13-p];
        c32 v[8];
        #pragma unroll
        for (int s = 0; s < 8; ++s) {
            int e = s ^ t7;
            float f = ph * ((e & 4) ? encs[11] : encc[11])
                         * ((e & 2) ? encs[12] : encc[12])
                         * ((e & 1) ? encs[13] : encc[13]);
            v[s] = { vh.x * f, vh.y * f };
        }
        gate8sw(v, Um[0][11], 4, (t7 >> 2) & 1);
        gate8sw(v, Um[0][12], 2, (t7 >> 1) & 1);
        gate8sw(v, Um[0][13], 1,  t7       & 1);
        #pragma unroll
        for (int s = 0; s < 8; ++s) st[base | (s ^ t7)] = make_float2(v[s].x, v[s].y);
    }
    __syncthreads();

    // ---- layer 0: remaining rotations + entangle gather (dump #1) ----
    sweepS3<10>(st, Um[0][1], Um[0][2], Um[0][3], tid); __syncthreads();  // q1,2,3
    sweepS3<7 >(st, Um[0][4], Um[0][5], Um[0][6], tid); __syncthreads();  // q4,5,6
    sweepS3<4 >(st, Um[0][7], Um[0][8], Um[0][9], tid); __syncthreads();  // q7,8,9
    sweepS1(st, Um[0][10], tid); __syncthreads();                          // q10
    gatherS(st, myd, tlo[0], thi[0], tid, hb12);
    __syncthreads();
    if (tid == 0) flag_set(&dumpF[bid], 1);

    // ---- layers 1..3 ----
    #pragma unroll 1
    for (int l = 1; l < NL; ++l) {
        if (tid == 0) flag_wait(&dumpF[pb], l);
        __syncthreads();
        sweepSA(st, pd, Um[l][0], Um[l][11], Um[l][12], Um[l][13], tid, h);
        __syncthreads();
        if (l < 3 && tid == 0) flag_set(&consF[bid], l);   // partner may overwrite its dump
        sweepS3<10>(st, Um[l][1], Um[l][2], Um[l][3], tid); __syncthreads();
        sweepS3<7 >(st, Um[l][4], Um[l][5], Um[l][6], tid); __syncthreads();
        sweepS3<4 >(st, Um[l][7], Um[l][8], Um[l][9], tid); __syncthreads();
        sweepS1(st, Um[l][10], tid); __syncthreads();
        if (l < 3) {
            if (tid == 0) flag_wait(&consF[pb], l);        // partner consumed my dump #l
            __syncthreads();
            gatherS(st, myd, tlo[l], thi[l], tid, hb12);
            __syncthreads();
            if (tid == 0) flag_set(&dumpF[bid], l + 1);
        }
    }

    // ---- epilogue: layer-3 gather+phase fused with <Z_i>; cross-block combine ----
    float acc[NQ];
    #pragma unroll
    for (int i = 0; i < NQ; ++i) acc[i] = 0.f;
    #pragma unroll
    for (int m = 0; m < 8; ++m) {
        int z = tid + m*NTS;
        int a = (z ^ (z >> 1)) ^ hb12;
        float2 f = st[a];
        float ang = tlo[NL-1][z & 127] + thi[NL-1][(z >> 7) & 63];
        float sn, cs;
        __sincosf(ang, &sn, &cs);
        float re = cs*f.x - sn*f.y;
        float im = cs*f.y + sn*f.x;
        float pr = re*re + im*im;
        acc[0] += h ? -pr : pr;              // qubit 0 = bit 13 = h
        #pragma unroll
        for (int p = 0; p <= 12; ++p)        // qubit 13-p at local bit p
            acc[13-p] += ((z >> p) & 1) ? -pr : pr;
    }
    #pragma unroll
    for (int off = 32; off >= 1; off >>= 1) {
        #pragma unroll
        for (int i = 0; i < NQ; ++i)
            acc[i] += __shfl_down(acc[i], off, 64);
    }
    const int wid = tid >> 6, lane = tid & 63;
    if (lane == 0) {
        #pragma unroll
        for (int i = 0; i < NQ; ++i) red[wid][i] = acc[i];
    }
    __syncthreads();
    float s = 0.f;
    if (tid < NQ) {
        #pragma unroll
        for (int w = 0; w < NTS/64; ++w) s += red[w][tid];
    }
    if (h == 1) {
        if (tid < NQ) part[bid*16 + tid] = s;
        __syncthreads();
        if (tid == 0) flag_set(&dumpF[bid], 4);
    } else {
        if (tid == 0) flag_wait(&dumpF[pb], 4);
        __syncthreads();
        if (tid < NQ) out[samp*NQ + tid] = s + part[pb*16 + tid];
    }
}

// ===========================================================================
// FALLBACK (round-7 kernel, verified): one block per sample, full state.
// Used only if ws_size is too small for the split path or B != 128.
// ===========================================================================
template<int L> __device__ __forceinline__ int permP(int y) {
    if constexpr (L == 0) return y;
    else if constexpr (L == 1) return y ^ (y >> 1);
    else if constexpr (L == 2) return y ^ (y >> 2);
    else if constexpr (L == 3) { int t = y ^ (y >> 1); return t ^ (t >> 2); }
    else return y ^ (y >> 4);
}

template<int L, int PB, bool FUSE>
__device__ __forceinline__ void sweep3(float2* st, const float* U2, const float* U1,
                                       const float* U0, const float* phlo, const float* phhi, int tid) {
    #pragma unroll 1
    for (int m = 0; m < 2; ++m) {
        const int t  = tid + m*NT;
        const int ib = ((t >> PB) << (PB+3)) | (t & ((1 << PB) - 1));
        c32 v[8]; int ad[8];
        #pragma unroll
        for (int k = 0; k < 8; ++k) {
            int y = ib + (k << PB);
            int a = permP<L>(y);
            ad[k] = a;
            float2 f = st[a];
            c32 vv = {f.x, f.y};
            if constexpr (FUSE) {
                float ang = phlo[y & 127] + phhi[(y >> 7) & 63];
                float sn, cs;
                __sincosf(ang, &sn, &cs);
                vv = { cs*vv.x - sn*vv.y, cs*vv.y + sn*vv.x };
            }
            v[k] = vv;
        }
        gate8(v, U2, 4); gate8(v, U1, 2); gate8(v, U0, 1);
        #pragma unroll
        for (int k = 0; k < 8; ++k) st[ad[k]] = make_float2(v[k].x, v[k].y);
    }
}

template<int L>
__device__ __forceinline__ void sweep2_43(float2* st, const float* U4, const float* U3, int tid) {
    #pragma unroll 1
    for (int m = 0; m < 4; ++m) {
        const int t  = tid + m*NT;
        const int ib = ((t >> 3) << 5) | (t & 7);
        c32 v[4]; int ad[4];
        #pragma unroll
        for (int k = 0; k < 4; ++k) {
            int y = ib + ((k & 1) << 3) + ((k >> 1) << 4);
            int a = permP<L>(y);
            ad[k] = a;
            float2 f = st[a];
            v[k] = {f.x, f.y};
        }
        {
            c32 u00={U4[0],U4[1]}, u01={U4[2],U4[3]}, u10={U4[4],U4[5]}, u11={U4[6],U4[7]};
            #pragma unroll
            for (int k = 0; k < 4; ++k) {
                if (k & 2) continue;
                c32 A = v[k], B = v[k|2];
                v[k]   = cadd(cmul(u00,A), cmul(u01,B));
                v[k|2] = cadd(cmul(u10,A), cmul(u11,B));
            }
        }
        {
            c32 u00={U3[0],U3[1]}, u01={U3[2],U3[3]}, u10={U3[4],U3[5]}, u11={U3[6],U3[7]};
            #pragma unroll
            for (int k = 0; k < 4; ++k) {
                if (k & 1) continue;
                c32 A = v[k], B = v[k|1];
                v[k]   = cadd(cmul(u00,A), cmul(u01,B));
                v[k|1] = cadd(cmul(u10,A), cmul(u11,B));
            }
        }
        #pragma unroll
        for (int k = 0; k < 4; ++k) st[ad[k]] = make_float2(v[k].x, v[k].y);
    }
}

template<int L>
__device__ __forceinline__ void sweep_own(float2* st, const float* U11, const float* U12,
                                          const float* U13, int tid) {
    const int t4   = tid & 15;
    const int base = tid << 4;
    #pragma unroll 1
    for (int m = 0; m < 2; ++m) {
        c32 v[8]; int ad[8];
        #pragma unroll
        for (int s = 0; s < 8; ++s) {
            int e = ((m << 3) | s) ^ t4;
            int a = permP<L>(base | e);
            ad[s] = a;
            float2 f = st[a];
            v[s] = {f.x, f.y};
        }
        gate8sw(v, U11, 4, (t4 >> 2) & 1);
        gate8sw(v, U12, 2, (t4 >> 1) & 1);
        gate8sw(v, U13, 1,  t4       & 1);
        #pragma unroll
        for (int s = 0; s < 8; ++s) st[ad[s]] = make_float2(v[s].x, v[s].y);
    }
}

template<int L>
__device__ __forceinline__ void do_layer(float2* st, float (*UmL)[8],
                                         const float* phlo, const float* phhi, int tid) {
    constexpr bool F = (L > 0);
    sweep3<L, 11, F>(st, UmL[0], UmL[1], UmL[2], phlo, phhi, tid);
    __syncthreads();
    sweep3<L, 8, false>(st, UmL[3], UmL[4], UmL[5], nullptr, nullptr, tid);
    __syncthreads();
    sweep3<L, 5, false>(st, UmL[6], UmL[7], UmL[8], nullptr, nullptr, tid);
    __syncthreads();
    sweep2_43<L>(st, UmL[9], UmL[10], tid);
    __syncthreads();
    sweep_own<L>(st, UmL[11], UmL[12], UmL[13], tid);
    __syncthreads();
}

__global__ __launch_bounds__(NT) __attribute__((amdgpu_waves_per_eu(4, 4)))
void qc_kernel(const float* __restrict__ x,
               const float* __restrict__ prx,
               const float* __restrict__ pry,
               const float* __restrict__ prz,
               const float* __restrict__ pent,
               float* __restrict__ out)
{
    __shared__ float2 st[NS];
    __shared__ float  Um[NL][NQ][8];
    __shared__ float  tlo[NL][128];
    __shared__ float  thi[NL][64];
    __shared__ float  encc[NQ], encs[NQ];
    __shared__ float  red[NT/64][NQ];

    const int tid = threadIdx.x;
    const int b   = blockIdx.x;

    precompute(x, prx, pry, prz, pent, Um, tlo, thi, encc, encs, tid, b);
    __syncthreads();

    {
        float prodLow = 1.f;
        #pragma unroll
        for (int p = 0; p < 10; ++p)
            prodLow *= ((tid >> p) & 1) ? encs[13-p] : encc[13-p];
        #pragma unroll
        for (int j = 0; j < APT; ++j) {
            float a = prodLow;
            a *= (j & 1) ? encs[3] : encc[3];
            a *= (j & 2) ? encs[2] : encc[2];
            a *= (j & 4) ? encs[1] : encc[1];
            a *= (j & 8) ? encs[0] : encc[0];
            st[tid + j*NT] = make_float2(a, 0.f);
        }
    }
    __syncthreads();

    do_layer<0>(st, Um[0], nullptr, nullptr, tid);
    do_layer<1>(st, Um[1], tlo[0], thi[0], tid);
    do_layer<2>(st, Um[2], tlo[1], thi[1], tid);
    do_layer<3>(st, Um[3], tlo[2], thi[2], tid);

    float acc[NQ];
    #pragma unroll
    for (int i = 0; i < NQ; ++i) acc[i] = 0.f;
    #pragma unroll
    for (int j = 0; j < APT; ++j) {
        int y = tid + j*NT;
        int a = permP<4>(y);
        float2 v = st[a];
        float ang = tlo[NL-1][y & 127] + thi[NL-1][(y >> 7) & 63];
        float sn, cs;
        __sincosf(ang, &sn, &cs);
        float re = cs*v.x - sn*v.y;
        float im = cs*v.y + sn*v.x;
        float pr = re*re + im*im;
        #pragma unroll
        for (int p = 0; p < NQ; ++p)
            acc[NQ-1-p] += ((y >> p) & 1) ? -pr : pr;
    }
    #pragma unroll
    for (int off = 32; off >= 1; off >>= 1) {
        #pragma unroll
        for (int i = 0; i < NQ; ++i)
            acc[i] += __shfl_down(acc[i], off, 64);
    }
    const int wid = tid >> 6, lane = tid & 63;
    if (lane == 0) {
        #pragma unroll
        for (int i = 0; i < NQ; ++i) red[wid][i] = acc[i];
    }
    __syncthreads();
    if (tid < NQ) {
        float s = 0.f;
        #pragma unroll
        for (int w = 0; w < NT/64; ++w) s += red[w][tid];
        out[b*NQ + tid] = s;
    }
}

extern "C" void kernel_launch(void* const* d_in, const int* in_sizes, int n_in,
                              void* d_out, int out_size, void* d_ws, size_t ws_size,
                              hipStream_t stream) {
    (void)n_in; (void)out_size;
    const float* x    = (const float*)d_in[0];
    const float* prx  = (const float*)d_in[1];
    const float* pry  = (const float*)d_in[2];
    const float* prz  = (const float*)d_in[3];
    const float* pent = (const float*)d_in[4];
    float* out = (float*)d_out;
    const int B = in_sizes[0] / NQ;
    const int nb = 2 * B;

    const size_t pdataBytes = (size_t)nb * NSH * sizeof(float2);     // 16 MB @ B=128
    const size_t flagsOff   = pdataBytes;                            // dumpF[nb]
    const size_t consOff    = flagsOff + 2048;                       // consF[nb]
    const size_t partOff    = flagsOff + 4096;                       // part[nb*16]
    const size_t need       = partOff + (size_t)nb * 16 * sizeof(float);

    if (ws_size >= need && B == 128) {
        char* wsb = (char*)d_ws;
        float2* pdata = (float2*)wsb;
        int*    dumpF = (int*)(wsb + flagsOff);
        int*    consF = (int*)(wsb + consOff);
        float*  part  = (float*)(wsb + partOff);
        hipMemsetAsync(wsb + flagsOff, 0, 4096, stream);             // zero flags each launch
        qc_split<<<nb, NTS, 0, stream>>>(x, prx, pry, prz, pent, out,
                                         pdata, dumpF, consF, part);
    } else {
        qc_kernel<<<B, NT, 0, stream>>>(x, prx, pry, prz, pent, out);
    }
}

// Round 10
// 141.898 us; speedup vs baseline: 1.7670x; 1.7425x over previous
//
#include <hip/hip_runtime.h>
#include <math.h>

#define NQ 14
#define NL 4
#define NS (1 << NQ)      // 16384 amplitudes
#define NT 1024           // threads per block
#define APT (NS / NT)     // 16 amps per thread

struct c32 { float x, y; };
__device__ __forceinline__ c32 cmul(c32 a, c32 b) { return {a.x*b.x - a.y*b.y, a.x*b.y + a.y*b.x}; }
__device__ __forceinline__ c32 cadd(c32 a, c32 b) { return {a.x + b.x, a.y + b.y}; }

// 16-slot butterfly network; U reloaded from LDS per call (2x float4) to keep
// the live set ~50 regs under the compiler's fixed 64-VGPR budget.
__device__ __forceinline__ void gate16(c32* v, const float* U, const int s) {
    float4 u0 = *(const float4*)U;        // u00.x u00.y u01.x u01.y
    float4 u1 = *(const float4*)(U + 4);  // u10.x u10.y u11.x u11.y
    c32 a00={u0.x,u0.y}, a01={u0.z,u0.w}, a10={u1.x,u1.y}, a11={u1.z,u1.w};
    #pragma unroll
    for (int k = 0; k < 16; ++k) {
        if (k & s) continue;
        c32 A = v[k], B = v[k | s];
        v[k]     = cadd(cmul(a00, A), cmul(a01, B));
        v[k | s] = cadd(cmul(a10, A), cmul(a11, B));
    }
}

__device__ __forceinline__ void gate8(c32* v, const float* U, const int s) {
    float4 u0 = *(const float4*)U;
    float4 u1 = *(const float4*)(U + 4);
    c32 a00={u0.x,u0.y}, a01={u0.z,u0.w}, a10={u1.x,u1.y}, a11={u1.z,u1.w};
    #pragma unroll
    for (int k = 0; k < 8; ++k) {
        if (k & s) continue;
        c32 A = v[k], B = v[k | s];
        v[k]     = cadd(cmul(a00, A), cmul(a01, B));
        v[k | s] = cadd(cmul(a10, A), cmul(a11, B));
    }
}

// Slot k holds logical element k^swbits (XOR bank-spread order): gate on a
// swizzled bit uses role-swapped U'[i][j] = U[i^sw][j^sw] (r6/r7-verified).
__device__ __forceinline__ void gate8sw(c32* v, const float* U, const int s, const int sw) {
    float4 u0 = *(const float4*)U;
    float4 u1 = *(const float4*)(U + 4);
    c32 n00={u0.x,u0.y}, n01={u0.z,u0.w}, n10={u1.x,u1.y}, n11={u1.z,u1.w};
    c32 a00 = sw ? n11 : n00;
    c32 a01 = sw ? n10 : n01;
    c32 a10 = sw ? n01 : n10;
    c32 a11 = sw ? n00 : n11;
    #pragma unroll
    for (int k = 0; k < 8; ++k) {
        if (k & s) continue;
        c32 A = v[k], B = v[k | s];
        v[k]     = cadd(cmul(a00, A), cmul(a01, B));
        v[k | s] = cadd(cmul(a10, A), cmul(a11, B));
    }
}

// ---------------------------------------------------------------------------
// Precompute (verified r1-r9): fused U = Rz*Ry*Rx per (layer,qubit), entangle
// phase tables over bits 0-12 (qubit 0 is never an RZ target), enc angles.
// ---------------------------------------------------------------------------
__device__ __forceinline__ void precompute(const float* x, const float* prx, const float* pry,
                                           const float* prz, const float* pent,
                                           float (*Um)[NQ][8], float (*tlo)[128], float (*thi)[64],
                                           float* encc, float* encs, int tid, int samp) {
    if (tid < NL*NQ) {
        int l = tid / NQ, q = tid % NQ;
        float hx = 0.5f*prx[l*NQ+q], hy = 0.5f*pry[l*NQ+q], hz = 0.5f*prz[l*NQ+q];
        float cx = cosf(hx), sx = sinf(hx);
        float cy = cosf(hy), sy = sinf(hy);
        float cz = cosf(hz), sz = sinf(hz);
        c32 m00 = { cy*cx,  sy*sx };
        c32 m01 = {-sy*cx, -cy*sx };
        c32 m10 = { sy*cx, -cy*sx };
        c32 m11 = { cy*cx, -sy*sx };
        c32 e0 = {cz, -sz}, e1 = {cz, sz};
        c32 u00 = cmul(e0, m00), u01 = cmul(e0, m01);
        c32 u10 = cmul(e1, m10), u11 = cmul(e1, m11);
        float* U = Um[l][q];
        U[0]=u00.x; U[1]=u00.y; U[2]=u01.x; U[3]=u01.y;
        U[4]=u10.x; U[5]=u10.y; U[6]=u11.x; U[7]=u11.y;
    } else if (tid >= 64 && tid < 64 + NL*192) {
        int t2 = tid - 64;
        int l = t2 / 192, r = t2 % 192;
        if (r < 128) {                       // bit positions 0..6, theta index 12-p
            float a = 0.f;
            for (int p = 0; p < 7; ++p) {
                float th = 0.5f * pent[l*(NQ-1) + (12 - p)];
                a += ((r >> p) & 1) ? th : -th;
            }
            tlo[l][r] = a;
        } else {                             // positions 7..12, theta index 5-p'
            int m = r - 128;
            float a = 0.f;
            for (int p = 0; p < 6; ++p) {
                float th = 0.5f * pent[l*(NQ-1) + (5 - p)];
                a += ((m >> p) & 1) ? th : -th;
            }
            thi[l][m] = a;
        }
    } else if (tid >= 960 && tid < 960 + NQ) {
        int i = tid - 960;
        float th = tanhf(x[samp*NQ + i]) * 3.14159265358979323846f;
        encc[i] = cosf(0.5f*th);
        encs[i] = sinf(0.5f*th);
    }
}

// ---- P2: qubits 4..7 (bits 9..6). Tuple = 16 amps at stride 64;
//      per-instruction lane addresses are consecutive -> conflict-free. ----
__device__ __forceinline__ void passP2(float2* st, const float (*UmL)[8], int tid) {
    const int ib = ((tid >> 6) << 10) | (tid & 63);
    c32 v[16];
    #pragma unroll
    for (int k = 0; k < 16; ++k) { float2 f = st[ib + k*64]; v[k] = {f.x, f.y}; }
    gate16(v, UmL[4], 8);   // q4 at bit 9 = k bit 3
    gate16(v, UmL[5], 4);   // q5
    gate16(v, UmL[6], 2);   // q6
    gate16(v, UmL[7], 1);   // q7
    #pragma unroll
    for (int k = 0; k < 16; ++k) st[ib + k*64] = make_float2(v[k].x, v[k].y);
}

// ---- P3: qubits 8..10 (bits 5..3). Two 8-amp tuples at stride 8. ----
__device__ __forceinline__ void passP3(float2* st, const float (*UmL)[8], int tid) {
    #pragma unroll 1
    for (int m = 0; m < 2; ++m) {
        const int T  = tid + m*NT;
        const int ib = ((T >> 3) << 6) | (T & 7);
        c32 v[8];
        #pragma unroll
        for (int k = 0; k < 8; ++k) { float2 f = st[ib + k*8]; v[k] = {f.x, f.y}; }
        gate8(v, UmL[8], 4);    // q8 at bit 5 = k bit 2
        gate8(v, UmL[9], 2);    // q9
        gate8(v, UmL[10], 1);   // q10
        #pragma unroll
        for (int k = 0; k < 8; ++k) st[ib + k*8] = make_float2(v[k].x, v[k].y);
    }
}

// ---- P4: qubits 11..13 (bits 2..0) on own 16 amps, XOR bank-spread order
//      + role-swapped matrices (r7-verified sweep_own, identity perm). ----
__device__ __forceinline__ void passP4(float2* st, const float (*UmL)[8], int tid) {
    const int t4   = tid & 15;
    const int base = tid << 4;
    #pragma unroll 1
    for (int m = 0; m < 2; ++m) {
        c32 v[8];
        #pragma unroll
        for (int s = 0; s < 8; ++s) {
            float2 f = st[base | (((m << 3) | s) ^ t4)];
            v[s] = {f.x, f.y};
        }
        gate8sw(v, UmL[11], 4, (t4 >> 2) & 1);
        gate8sw(v, UmL[12], 2, (t4 >> 1) & 1);
        gate8sw(v, UmL[13], 1,  t4       & 1);
        #pragma unroll
        for (int s = 0; s < 8; ++s)
            st[base | (((m << 3) | s) ^ t4)] = make_float2(v[s].x, v[s].y);
    }
}

__global__ __launch_bounds__(NT) __attribute__((amdgpu_waves_per_eu(4, 4)))
void qc_kernel(const float* __restrict__ x,
               const float* __restrict__ prx,
               const float* __restrict__ pry,
               const float* __restrict__ prz,
               const float* __restrict__ pent,
               float* __restrict__ out)
{
    __shared__ float2 st[NS];            // 128 KB state (always natural order)
    __shared__ float  Um[NL][NQ][8];
    __shared__ float  tlo[NL][128];
    __shared__ float  thi[NL][64];
    __shared__ float  encc[NQ], encs[NQ];
    __shared__ float  red[NT/64][NQ];

    const int tid = threadIdx.x;
    const int b   = blockIdx.x;

    precompute(x, prx, pry, prz, pent, Um, tlo, thi, encc, encs, tid, b);
    __syncthreads();

    // ---- init fused with layer-0 q0..q3: y = tid + j*1024, j = bits 13..10
    //      (qubits 0..3). Product state built in-register, no LDS read. ----
    {
        float prodLow = 1.f;
        #pragma unroll
        for (int p = 0; p < 10; ++p)         // y bit p (p=0..9) <-> qubit 13-p
            prodLow *= ((tid >> p) & 1) ? encs[13-p] : encc[13-p];
        c32 v[16];
        #pragma unroll
        for (int j = 0; j < 16; ++j) {
            float a = prodLow
                    * ((j & 8) ? encs[0] : encc[0])
                    * ((j & 4) ? encs[1] : encc[1])
                    * ((j & 2) ? encs[2] : encc[2])
                    * ((j & 1) ? encs[3] : encc[3]);
            v[j] = { a, 0.f };
        }
        gate16(v, Um[0][0], 8);              // q0 at bit 13 = j bit 3
        gate16(v, Um[0][1], 4);
        gate16(v, Um[0][2], 2);
        gate16(v, Um[0][3], 1);
        #pragma unroll
        for (int j = 0; j < 16; ++j) st[tid + j*NT] = make_float2(v[j].x, v[j].y);
    }
    __syncthreads();
    passP2(st, Um[0], tid); __syncthreads();
    passP3(st, Um[0], tid); __syncthreads();
    passP4(st, Um[0], tid); __syncthreads();

    // ---- layers 1..3: gather(entangle l-1) fused with q0..q3 of layer l ----
    #pragma unroll 1
    for (int l = 1; l < NL; ++l) {
        {
            const float* phlo = tlo[l-1];
            const float* phhi = thi[l-1];
            c32 v[16];
            #pragma unroll
            for (int j = 0; j < 16; ++j) {   // read-all (pre-gather state)
                int y  = tid + j*NT;
                int a  = y ^ (y >> 1);       // gather source (verified r1-r9)
                float2 f = st[a];
                float ang = phlo[y & 127] + phhi[(y >> 7) & 63];
                float sn, cs;
                __sincosf(ang, &sn, &cs);
                v[j] = { cs*f.x - sn*f.y, cs*f.y + sn*f.x };
            }
            __syncthreads();                 // all reads done before any write
            gate16(v, Um[l][0], 8);          // q0..q3 on j-bits
            gate16(v, Um[l][1], 4);
            gate16(v, Um[l][2], 2);
            gate16(v, Um[l][3], 1);
            #pragma unroll
            for (int j = 0; j < 16; ++j) st[tid + j*NT] = make_float2(v[j].x, v[j].y);
        }
        __syncthreads();
        passP2(st, Um[l], tid); __syncthreads();
        passP3(st, Um[l], tid); __syncthreads();
        passP4(st, Um[l], tid); __syncthreads();
    }

    // ---- epilogue: layer-3 entangle (gather+phase) fused with <Z_i> ----
    float acc[NQ];
    #pragma unroll
    for (int i = 0; i < NQ; ++i) acc[i] = 0.f;
    #pragma unroll
    for (int j = 0; j < APT; ++j) {
        int y = tid + j*NT;
        int a = y ^ (y >> 1);
        float2 f = st[a];
        float ang = tlo[NL-1][y & 127] + thi[NL-1][(y >> 7) & 63];
        float sn, cs;
        __sincosf(ang, &sn, &cs);
        float re = cs*f.x - sn*f.y;
        float im = cs*f.y + sn*f.x;
        float pr = re*re + im*im;
        #pragma unroll
        for (int p = 0; p < NQ; ++p)         // qubit NQ-1-p at bit position p
            acc[NQ-1-p] += ((y >> p) & 1) ? -pr : pr;
    }
    #pragma unroll
    for (int off = 32; off >= 1; off >>= 1) {
        #pragma unroll
        for (int i = 0; i < NQ; ++i)
            acc[i] += __shfl_down(acc[i], off, 64);
    }
    const int wid = tid >> 6, lane = tid & 63;
    if (lane == 0) {
        #pragma unroll
        for (int i = 0; i < NQ; ++i) red[wid][i] = acc[i];
    }
    __syncthreads();
    if (tid < NQ) {
        float s = 0.f;
        #pragma unroll
        for (int w = 0; w < NT/64; ++w) s += red[w][tid];
        out[b*NQ + tid] = s;
    }
}

extern "C" void kernel_launch(void* const* d_in, const int* in_sizes, int n_in,
                              void* d_out, int out_size, void* d_ws, size_t ws_size,
                              hipStream_t stream) {
    (void)d_ws; (void)ws_size; (void)n_in; (void)out_size;
    const float* x    = (const float*)d_in[0];
    const float* prx  = (const float*)d_in[1];
    const float* pry  = (const float*)d_in[2];
    const float* prz  = (const float*)d_in[3];
    const float* pent = (const float*)d_in[4];
    float* out = (float*)d_out;
    const int B = in_sizes[0] / NQ;
    qc_kernel<<<B, NT, 0, stream>>>(x, prx, pry, prz, pent, out);
}

// Round 11
// 132.575 us; speedup vs baseline: 1.8913x; 1.0703x over previous
//
#include <hip/hip_runtime.h>
#include <math.h>

#define NQ 14
#define NL 4
#define NS (1 << NQ)      // 16384 amplitudes
#define NT 1024           // threads per block
#define APT (NS / NT)     // 16 amps per thread

struct c32 { float x, y; };
__device__ __forceinline__ c32 cmul(c32 a, c32 b) { return {a.x*b.x - a.y*b.y, a.x*b.y + a.y*b.x}; }
__device__ __forceinline__ c32 cadd(c32 a, c32 b) { return {a.x + b.x, a.y + b.y}; }

// phase (p1*p2) applied to f — replaces __sincosf with 2 cmuls on main VALU
__device__ __forceinline__ c32 phase_mul(float2 p1, float2 p2, float2 f) {
    c32 ph = { p1.x*p2.x - p1.y*p2.y, p1.x*p2.y + p1.y*p2.x };
    return { ph.x*f.x - ph.y*f.y, ph.x*f.y + ph.y*f.x };
}

// Butterfly gates; U reloaded per call (2x float4) to cap live registers.
__device__ __forceinline__ void gate8(c32* v, const float* U, const int s) {
    float4 u0 = *(const float4*)U;
    float4 u1 = *(const float4*)(U + 4);
    c32 a00={u0.x,u0.y}, a01={u0.z,u0.w}, a10={u1.x,u1.y}, a11={u1.z,u1.w};
    #pragma unroll
    for (int k = 0; k < 8; ++k) {
        if (k & s) continue;
        c32 A = v[k], B = v[k | s];
        v[k]     = cadd(cmul(a00, A), cmul(a01, B));
        v[k | s] = cadd(cmul(a10, A), cmul(a11, B));
    }
}

__device__ __forceinline__ void gate4(c32* v, const float* U, const int s) {
    float4 u0 = *(const float4*)U;
    float4 u1 = *(const float4*)(U + 4);
    c32 a00={u0.x,u0.y}, a01={u0.z,u0.w}, a10={u1.x,u1.y}, a11={u1.z,u1.w};
    #pragma unroll
    for (int k = 0; k < 4; ++k) {
        if (k & s) continue;
        c32 A = v[k], B = v[k | s];
        v[k]     = cadd(cmul(a00, A), cmul(a01, B));
        v[k | s] = cadd(cmul(a10, A), cmul(a11, B));
    }
}

// Slot k holds logical element k^swbits: role-swapped U'[i][j]=U[i^sw][j^sw]
// (r6/r7-verified).
__device__ __forceinline__ void gate8sw(c32* v, const float* U, const int s, const int sw) {
    float4 u0 = *(const float4*)U;
    float4 u1 = *(const float4*)(U + 4);
    c32 n00={u0.x,u0.y}, n01={u0.z,u0.w}, n10={u1.x,u1.y}, n11={u1.z,u1.w};
    c32 a00 = sw ? n11 : n00;
    c32 a01 = sw ? n10 : n01;
    c32 a10 = sw ? n01 : n10;
    c32 a11 = sw ? n00 : n11;
    #pragma unroll
    for (int k = 0; k < 8; ++k) {
        if (k & s) continue;
        c32 A = v[k], B = v[k | s];
        v[k]     = cadd(cmul(a00, A), cmul(a01, B));
        v[k | s] = cadd(cmul(a10, A), cmul(a11, B));
    }
}

__global__ __launch_bounds__(NT) __attribute__((amdgpu_waves_per_eu(4, 4)))
void qc_kernel(const float* __restrict__ x,
               const float* __restrict__ prx,
               const float* __restrict__ pry,
               const float* __restrict__ prz,
               const float* __restrict__ pent,
               float* __restrict__ out)
{
    __shared__ float2 st[NS];            // 128 KB state, always natural order
    __shared__ float  Um[NL][NQ][8];     // fused Rz*Ry*Rx per (layer,qubit)
    __shared__ float2 tloc[NL][128];     // entangle phase (cos,sin), bits 0..6
    __shared__ float2 thic[NL][64];      // bits 7..12
    __shared__ float  encc[NQ], encs[NQ];
    __shared__ float  red[NT/64][NQ];

    const int tid = threadIdx.x;
    const int b   = blockIdx.x;

    // ---------------- precompute (verified r1-r10; tables now (cos,sin)) ----
    if (tid < NL*NQ) {
        int l = tid / NQ, q = tid % NQ;
        float hx = 0.5f*prx[l*NQ+q], hy = 0.5f*pry[l*NQ+q], hz = 0.5f*prz[l*NQ+q];
        float cx = cosf(hx), sx = sinf(hx);
        float cy = cosf(hy), sy = sinf(hy);
        float cz = cosf(hz), sz = sinf(hz);
        c32 m00 = { cy*cx,  sy*sx };
        c32 m01 = {-sy*cx, -cy*sx };
        c32 m10 = { sy*cx, -cy*sx };
        c32 m11 = { cy*cx, -sy*sx };
        c32 e0 = {cz, -sz}, e1 = {cz, sz};
        c32 u00 = cmul(e0, m00), u01 = cmul(e0, m01);
        c32 u10 = cmul(e1, m10), u11 = cmul(e1, m11);
        float* U = Um[l][q];
        U[0]=u00.x; U[1]=u00.y; U[2]=u01.x; U[3]=u01.y;
        U[4]=u10.x; U[5]=u10.y; U[6]=u11.x; U[7]=u11.y;
    } else if (tid >= 64 && tid < 64 + NL*192) {
        int t2 = tid - 64;
        int l = t2 / 192, r = t2 % 192;
        if (r < 128) {                       // bit positions 0..6, theta 12-p
            float a = 0.f;
            for (int p = 0; p < 7; ++p) {
                float th = 0.5f * pent[l*(NQ-1) + (12 - p)];
                a += ((r >> p) & 1) ? th : -th;
            }
            tloc[l][r] = make_float2(cosf(a), sinf(a));
        } else {                             // positions 7..12, theta 5-p'
            int m = r - 128;
            float a = 0.f;
            for (int p = 0; p < 6; ++p) {
                float th = 0.5f * pent[l*(NQ-1) + (5 - p)];
                a += ((m >> p) & 1) ? th : -th;
            }
            thic[l][m] = make_float2(cosf(a), sinf(a));
        }
    } else if (tid >= 960 && tid < 960 + NQ) {
        int i = tid - 960;
        float th = tanhf(x[b*NQ + i]) * 3.14159265358979323846f;
        encc[i] = cosf(0.5f*th);
        encs[i] = sinf(0.5f*th);
    }
    __syncthreads();

    // ---- init = layer-0 "S1": product state + q1,q2,q3 in-register.
    //      y = (h<<13) + (m<<10) + tid; q0 handled in S2 like every layer. ----
    {
        float prodT = 1.f;
        #pragma unroll
        for (int p = 0; p < 10; ++p)         // y bit p <-> qubit 13-p
            prodT *= ((tid >> p) & 1) ? encs[13-p] : encc[13-p];
        #pragma unroll 1
        for (int h = 0; h < 2; ++h) {
            float ah = prodT * (h ? encs[0] : encc[0]);
            c32 v[8];
            #pragma unroll
            for (int m = 0; m < 8; ++m) {
                float a = ah
                        * ((m & 4) ? encs[1] : encc[1])
                        * ((m & 2) ? encs[2] : encc[2])
                        * ((m & 1) ? encs[3] : encc[3]);
                v[m] = { a, 0.f };
            }
            gate8(v, Um[0][1], 4);           // q1 at y bit 12 = m bit 2
            gate8(v, Um[0][2], 2);
            gate8(v, Um[0][3], 1);
            const int yb = (h << 13) | tid;
            #pragma unroll
            for (int m = 0; m < 8; ++m) st[yb + (m << 10)] = make_float2(v[m].x, v[m].y);
        }
    }
    __syncthreads();

    #pragma unroll 1
    for (int l = 0; l < NL; ++l) {
        // ---- S1 (l>=1): entangle(l-1) gather+phase fused with q1,q2,q3.
        //      Gray perm preserves bit 13 -> two half-sweeps are safe with
        //      one read/write barrier each (r4/r6-verified split). ----
        if (l > 0) {
            #pragma unroll 1
            for (int h = 0; h < 2; ++h) {
                const int yb = (h << 13) | tid;
                c32 v[8];
                #pragma unroll
                for (int m = 0; m < 8; ++m) {
                    int y = yb + (m << 10);
                    int a = y ^ (y >> 1);    // gather source (verified r1-r10)
                    float2 f = st[a];
                    v[m] = phase_mul(tloc[l-1][y & 127], thic[l-1][(y >> 7) & 63], f);
                }
                gate8(v, Um[l][1], 4);       // q1 at y bit 12 = m bit 2
                gate8(v, Um[l][2], 2);
                gate8(v, Um[l][3], 1);
                __syncthreads();             // all reads of this half done
                #pragma unroll
                for (int m = 0; m < 8; ++m) st[yb + (m << 10)] = make_float2(v[m].x, v[m].y);
            }
            __syncthreads();
        }

        // ---- S2: q0,q4,q5 (bits 13,9,8); thread-exclusive 8-amp tuples ----
        #pragma unroll 1
        for (int m = 0; m < 2; ++m) {
            const int T  = tid + (m << 10);
            const int ib = ((T >> 8) << 10) | (T & 255);
            c32 v[8];
            #pragma unroll
            for (int k = 0; k < 8; ++k) {
                int a = ib + ((k & 4) ? 8192 : 0) + ((k & 2) ? 512 : 0) + ((k & 1) ? 256 : 0);
                float2 f = st[a];
                v[k] = {f.x, f.y};
            }
            gate8(v, Um[l][0], 4);           // q0 at bit 13 = k bit 2
            gate8(v, Um[l][4], 2);           // q4 at bit 9
            gate8(v, Um[l][5], 1);           // q5 at bit 8
            #pragma unroll
            for (int k = 0; k < 8; ++k) {
                int a = ib + ((k & 4) ? 8192 : 0) + ((k & 2) ? 512 : 0) + ((k & 1) ? 256 : 0);
                st[a] = make_float2(v[k].x, v[k].y);
            }
        }
        __syncthreads();

        // ---- S3: q6,q7,q8 (bits 7,6,5) ----
        #pragma unroll 1
        for (int m = 0; m < 2; ++m) {
            const int T  = tid + (m << 10);
            const int ib = ((T >> 5) << 8) | (T & 31);
            c32 v[8];
            #pragma unroll
            for (int k = 0; k < 8; ++k) { float2 f = st[ib + (k << 5)]; v[k] = {f.x, f.y}; }
            gate8(v, Um[l][6], 4);           // q6 at bit 7 = k bit 2
            gate8(v, Um[l][7], 2);
            gate8(v, Um[l][8], 1);
            #pragma unroll
            for (int k = 0; k < 8; ++k) st[ib + (k << 5)] = make_float2(v[k].x, v[k].y);
        }
        __syncthreads();

        // ---- S4: q9,q10 (bits 4,3) ----
        #pragma unroll 1
        for (int m = 0; m < 4; ++m) {
            const int T  = tid + (m << 10);
            const int ib = ((T >> 3) << 5) | (T & 7);
            c32 v[4];
            #pragma unroll
            for (int k = 0; k < 4; ++k) { float2 f = st[ib + (k << 3)]; v[k] = {f.x, f.y}; }
            gate4(v, Um[l][9], 2);           // q9 at bit 4 = k bit 1
            gate4(v, Um[l][10], 1);          // q10 at bit 3
            #pragma unroll
            for (int k = 0; k < 4; ++k) st[ib + (k << 3)] = make_float2(v[k].x, v[k].y);
        }
        __syncthreads();

        // ---- S5: own q11,q12,q13 (bits 2..0), XOR order + role swap
        //      (r7-verified passP4) ----
        {
            const int t4   = tid & 15;
            const int base = tid << 4;
            #pragma unroll 1
            for (int m = 0; m < 2; ++m) {
                c32 v[8];
                #pragma unroll
                for (int s = 0; s < 8; ++s) {
                    float2 f = st[base | (((m << 3) | s) ^ t4)];
                    v[s] = {f.x, f.y};
                }
                gate8sw(v, Um[l][11], 4, (t4 >> 2) & 1);
                gate8sw(v, Um[l][12], 2, (t4 >> 1) & 1);
                gate8sw(v, Um[l][13], 1,  t4       & 1);
                #pragma unroll
                for (int s = 0; s < 8; ++s)
                    st[base | (((m << 3) | s) ^ t4)] = make_float2(v[s].x, v[s].y);
            }
        }
        __syncthreads();
    }

    // ---- epilogue: entangle-3 (gather+phase) fused with <Z_i> ----
    float acc[NQ];
    #pragma unroll
    for (int i = 0; i < NQ; ++i) acc[i] = 0.f;
    #pragma unroll
    for (int j = 0; j < APT; ++j) {
        int y = tid + j*NT;
        int a = y ^ (y >> 1);
        float2 f = st[a];
        c32 r = phase_mul(tloc[NL-1][y & 127], thic[NL-1][(y >> 7) & 63], f);
        float pr = r.x*r.x + r.y*r.y;
        #pragma unroll
        for (int p = 0; p < NQ; ++p)         // qubit NQ-1-p at bit position p
            acc[NQ-1-p] += ((y >> p) & 1) ? -pr : pr;
    }
    #pragma unroll
    for (int off = 32; off >= 1; off >>= 1) {
        #pragma unroll
        for (int i = 0; i < NQ; ++i)
            acc[i] += __shfl_down(acc[i], off, 64);
    }
    const int wid = tid >> 6, lane = tid & 63;
    if (lane == 0) {
        #pragma unroll
        for (int i = 0; i < NQ; ++i) red[wid][i] = acc[i];
    }
    __syncthreads();
    if (tid < NQ) {
        float s = 0.f;
        #pragma unroll
        for (int w = 0; w < NT/64; ++w) s += red[w][tid];
        out[b*NQ + tid] = s;
    }
}

extern "C" void kernel_launch(void* const* d_in, const int* in_sizes, int n_in,
                              void* d_out, int out_size, void* d_ws, size_t ws_size,
                              hipStream_t stream) {
    (void)d_ws; (void)ws_size; (void)n_in; (void)out_size;
    const float* x    = (const float*)d_in[0];
    const float* prx  = (const float*)d_in[1];
    const float* pry  = (const float*)d_in[2];
    const float* prz  = (const float*)d_in[3];
    const float* pent = (const float*)d_in[4];
    float* out = (float*)d_out;
    const int B = in_sizes[0] / NQ;
    qc_kernel<<<B, NT, 0, stream>>>(x, prx, pry, prz, pent, out);
}